// Round 3
// 865.219 us; speedup vs baseline: 1.0401x; 1.0401x over previous
//
#include <hip/hip_runtime.h>
#include <hip/hip_bf16.h>
#include <stdint.h>

#define NB 4
#define NH 8
#define SDIM 2048
#define DDIM 64

// 1/sqrt(64) * log2(e) folded into K so softmax uses native base-2 exp (v_exp_f32).
// Softmax is invariant to the base change when applied consistently.
#define KSCALE 0.18033688011112042f

typedef short s8v __attribute__((ext_vector_type(8)));   // 8 x bf16 (bit pattern)
typedef float f4v __attribute__((ext_vector_type(4)));   // MFMA C/D + NT stores

__device__ __forceinline__ float bf2f(unsigned short h) {
    union { unsigned int u; float f; } c; c.u = ((unsigned int)h) << 16; return c.f;
}
__device__ __forceinline__ unsigned short f2bf(float x) {
    union { float f; unsigned int u; } c; c.f = x;
    return (unsigned short)((c.u + 0x7FFFu + ((c.u >> 16) & 1u)) >> 16);  // RNE
}

// ---------- prep 1: kb = bf16(k * KSCALE) ----------
__global__ void sdpa_prep_cast_k(const float* __restrict__ k, unsigned short* __restrict__ kb) {
    int i = blockIdx.x * 256 + threadIdx.x;           // grid covers exactly n/4 float4s
    float4 v = ((const float4*)k)[i];
    ushort4 o;
    o.x = f2bf(v.x * KSCALE);
    o.y = f2bf(v.y * KSCALE);
    o.z = f2bf(v.z * KSCALE);
    o.w = f2bf(v.w * KSCALE);
    ((ushort4*)kb)[i] = o;
}

// ---------- prep 2: vtb[bh][d][s] = bf16(v[bh][s][d])  (64x64 LDS tile transpose) ----------
__global__ void sdpa_prep_transpose_v(const float* __restrict__ v, unsigned short* __restrict__ vt) {
    __shared__ float t[64][65];
    const int bh = blockIdx.x >> 5;
    const int kt = blockIdx.x & 31;
    const int tid = threadIdx.x;
    const float* src = v + ((size_t)bh * SDIM + (size_t)kt * 64) * DDIM;
    #pragma unroll
    for (int i = 0; i < 4; ++i) {
        int idx = i * 256 + tid;
        int kl = idx >> 4, c4 = idx & 15;
        float4 val = ((const float4*)(src + kl * DDIM))[c4];
        t[kl][c4 * 4 + 0] = val.x; t[kl][c4 * 4 + 1] = val.y;
        t[kl][c4 * 4 + 2] = val.z; t[kl][c4 * 4 + 3] = val.w;
    }
    __syncthreads();
    const int d   = tid >> 2;
    const int klb = (tid & 3) << 4;
    unsigned short* dst = vt + ((size_t)bh * DDIM + d) * SDIM + kt * 64 + klb;
    #pragma unroll
    for (int c = 0; c < 4; ++c) {
        ushort4 w;
        w.x = f2bf(t[klb + c * 4 + 0][d]);
        w.y = f2bf(t[klb + c * 4 + 1][d]);
        w.z = f2bf(t[klb + c * 4 + 2][d]);
        w.w = f2bf(t[klb + c * 4 + 3][d]);
        ((ushort4*)dst)[c] = w;
    }
}

// ---------- main fused kernel: one block = 16 q-rows of one (b,h), 512 threads ----------
// LDS: sc[16][2048] bf16 = 65536 B (2 blocks/CU -> 16 waves/CU with 512-thread blocks).
// 16B-block XOR swizzle: element (row, col) -> row*2048 + ((col>>3) ^ row)*8 + (col&7)
__launch_bounds__(512, 4)
__global__ void sdpa_main(const float* __restrict__ q,
                          const unsigned short* __restrict__ kb,
                          const unsigned short* __restrict__ vtb,
                          const int* __restrict__ mask,
                          float* __restrict__ outO,
                          float* __restrict__ outP) {
    extern __shared__ char lds[];
    unsigned short* sc = (unsigned short*)lds;

    const int bx = blockIdx.x;
    const int bh = bx >> 7;            // 128 q-tiles per (b,h)
    const int q0 = (bx & 127) << 4;
    const int b  = bh >> 3;            // H = 8

    const int tid  = threadIdx.x;
    const int wave = tid >> 6;         // 0..7
    const int lane = tid & 63;
    const int l15  = lane & 15;
    const int quad = lane >> 4;

    // ---- Q A-fragments straight from global fp32: A[m=l15][k=ka*32+quad*8+j] ----
    s8v aq0, aq1;
    {
        const float* qr = q + ((size_t)bh * SDIM + q0 + l15) * DDIM + quad * 8;
        float4 x0 = ((const float4*)qr)[0];
        float4 x1 = ((const float4*)qr)[1];
        float4 y0 = ((const float4*)(qr + 32))[0];
        float4 y1 = ((const float4*)(qr + 32))[1];
        aq0[0]=(short)f2bf(x0.x); aq0[1]=(short)f2bf(x0.y); aq0[2]=(short)f2bf(x0.z); aq0[3]=(short)f2bf(x0.w);
        aq0[4]=(short)f2bf(x1.x); aq0[5]=(short)f2bf(x1.y); aq0[6]=(short)f2bf(x1.z); aq0[7]=(short)f2bf(x1.w);
        aq1[0]=(short)f2bf(y0.x); aq1[1]=(short)f2bf(y0.y); aq1[2]=(short)f2bf(y0.z); aq1[3]=(short)f2bf(y0.w);
        aq1[4]=(short)f2bf(y1.x); aq1[5]=(short)f2bf(y1.y); aq1[6]=(short)f2bf(y1.z); aq1[7]=(short)f2bf(y1.w);
    }

    // ---- phase 1: scores' = Q*(K*KSCALE)^T, wave w owns kpos [256w, 256w+256) ----
    {
        const unsigned short* kbase = kb + (size_t)bh * SDIM * DDIM;
        const int n_start = wave << 8;
        #pragma unroll 2
        for (int t = 0; t < 16; ++t) {
            const int n0 = n_start + (t << 4);
            const unsigned short* krow = kbase + (size_t)(n0 + l15) * DDIM + quad * 8;
            s8v b0 = *(const s8v*)(krow);
            s8v b1 = *(const s8v*)(krow + 32);
            f4v acc = {0.f, 0.f, 0.f, 0.f};
            acc = __builtin_amdgcn_mfma_f32_16x16x32_bf16(aq0, b0, acc, 0, 0, 0);
            acc = __builtin_amdgcn_mfma_f32_16x16x32_bf16(aq1, b1, acc, 0, 0, 0);
            const int col = n0 + l15;
            const int blk = col >> 3;
            const int off = col & 7;
            #pragma unroll
            for (int r = 0; r < 4; ++r) {
                int row = quad * 4 + r;                       // C row = q-row
                sc[row * 2048 + (((blk ^ row) << 3) | off)] = f2bf(acc[r]);
            }
        }
    }
    __syncthreads();

    // ---- fused softmax row pass: 32 threads per row, scores held in f32 registers ----
    const int row = tid >> 5;          // 0..15
    const int l32 = tid & 31;
    unsigned short* scrow = sc + row * 2048;
    const int* mrow = mask + (size_t)b * SDIM * SDIM + (size_t)(q0 + row) * SDIM;

    float s[64];
    float rmax = -3.0e38f;
    #pragma unroll
    for (int i = 0; i < 8; ++i) {
        const int j = l32 + (i << 5);                        // chunk 0..255
        s8v vv = *(const s8v*)(scrow + ((j ^ row) << 3));
        int4 m0 = ((const int4*)mrow)[j * 2 + 0];
        int4 m1 = ((const int4*)mrow)[j * 2 + 1];
        const int mm[8] = { m0.x, m0.y, m0.z, m0.w, m1.x, m1.y, m1.z, m1.w };
        #pragma unroll
        for (int e = 0; e < 8; ++e) {
            float x = bf2f((unsigned short)vv[e]);
            x = (mm[e] == 0) ? -1.0e9f : x;
            s[i * 8 + e] = x;
            rmax = fmaxf(rmax, x);
        }
    }
    #pragma unroll
    for (int d = 1; d < 32; d <<= 1) rmax = fmaxf(rmax, __shfl_xor(rmax, d));

    float rsum = 0.f;
    #pragma unroll
    for (int i = 0; i < 64; ++i) {
        float e = exp2f(s[i] - rmax);                        // base-2: log2e folded into K
        s[i] = e;
        rsum += e;
    }
    #pragma unroll
    for (int d = 1; d < 32; d <<= 1) rsum += __shfl_xor(rsum, d);
    const float rinv = 1.0f / rsum;

    {
        float* prow = outP + (size_t)bh * SDIM * SDIM + (size_t)(q0 + row) * SDIM;
        #pragma unroll
        for (int i = 0; i < 8; ++i) {
            const int j = l32 + (i << 5);
            float p0 = s[i*8+0] * rinv, p1 = s[i*8+1] * rinv;
            float p2 = s[i*8+2] * rinv, p3 = s[i*8+3] * rinv;
            float p4 = s[i*8+4] * rinv, p5 = s[i*8+5] * rinv;
            float p6 = s[i*8+6] * rinv, p7 = s[i*8+7] * rinv;
            f4v o0 = { p0, p1, p2, p3 };
            f4v o1 = { p4, p5, p6, p7 };
            __builtin_nontemporal_store(o0, (f4v*)prow + j * 2 + 0);   // 537 MB stream:
            __builtin_nontemporal_store(o1, (f4v*)prow + j * 2 + 1);   // don't pollute L2
            s8v vv;
            vv[0]=(short)f2bf(p0); vv[1]=(short)f2bf(p1); vv[2]=(short)f2bf(p2); vv[3]=(short)f2bf(p3);
            vv[4]=(short)f2bf(p4); vv[5]=(short)f2bf(p5); vv[6]=(short)f2bf(p6); vv[7]=(short)f2bf(p7);
            *(s8v*)(scrow + ((j ^ row) << 3)) = vv;
        }
    }
    __syncthreads();

    // ---- phase 4: O = P * V. Wave w: d-tile (w&3), k-half (w>>2). ----
    {
        const int dt = wave & 3;
        const int kh = wave >> 2;
        const unsigned short* vbase = vtb + ((size_t)bh * DDIM + (dt << 4) + l15) * SDIM
                                          + (kh << 10) + quad * 8;
        const unsigned short* arow = sc + l15 * 2048;        // A row m = l15 (q-row)
        f4v acc0 = {0,0,0,0}, acc1 = {0,0,0,0};
        #pragma unroll 4
        for (int ks = 0; ks < 32; ++ks) {
            const int k0 = (kh << 10) + (ks << 5);
            s8v a  = *(const s8v*)(arow + ((((k0 >> 3) + quad) ^ l15) << 3));
            s8v bb = *(const s8v*)(vbase + (ks << 5));
            if (ks & 1) acc1 = __builtin_amdgcn_mfma_f32_16x16x32_bf16(a, bb, acc1, 0, 0, 0);
            else        acc0 = __builtin_amdgcn_mfma_f32_16x16x32_bf16(a, bb, acc0, 0, 0, 0);
        }
        f4v acc = acc0 + acc1;

        __syncthreads();                                     // everyone done reading sc
        float* scratch = (float*)lds;                        // reuse score LDS: 4 KB
        if (kh == 1) {
            #pragma unroll
            for (int r = 0; r < 4; ++r)
                scratch[(dt << 8) + ((quad * 4 + r) << 4) + l15] = acc[r];
        }
        __syncthreads();
        if (kh == 0) {
            float* orow = outO + ((size_t)bh * SDIM + q0) * DDIM + (dt << 4) + l15;
            #pragma unroll
            for (int r = 0; r < 4; ++r)
                orow[(quad * 4 + r) * DDIM] = acc[r] + scratch[(dt << 8) + ((quad * 4 + r) << 4) + l15];
        }
    }
}

extern "C" void kernel_launch(void* const* d_in, const int* in_sizes, int n_in,
                              void* d_out, int out_size, void* d_ws, size_t ws_size,
                              hipStream_t stream) {
    const float* q  = (const float*)d_in[0];
    const float* k  = (const float*)d_in[1];
    const float* v  = (const float*)d_in[2];
    const int* mask = (const int*)d_in[3];

    const size_t qkv_elems = (size_t)NB * NH * SDIM * DDIM;     // 4,194,304
    float* outO = (float*)d_out;
    float* outP = (float*)d_out + qkv_elems;

    unsigned short* kb  = (unsigned short*)d_ws;                // 8 MB
    unsigned short* vtb = kb + qkv_elems;                       // 8 MB

    sdpa_prep_cast_k<<<(int)(qkv_elems / 1024), 256, 0, stream>>>(k, kb);
    sdpa_prep_transpose_v<<<NB * NH * (SDIM / 64), 256, 0, stream>>>(v, vtb);
    sdpa_main<<<NB * NH * (SDIM / 16), 512, 65536, stream>>>(q, kb, vtb, mask, outO, outP);
}

// Round 4
// 842.782 us; speedup vs baseline: 1.0678x; 1.0266x over previous
//
#include <hip/hip_runtime.h>
#include <hip/hip_bf16.h>
#include <stdint.h>

#define NB 4
#define NH 8
#define SDIM 2048
#define DDIM 64

// 1/sqrt(64) * log2(e) folded into K so softmax uses native base-2 exp (v_exp_f32).
// Softmax is invariant to the base change when applied consistently.
#define KSCALE 0.18033688011112042f

typedef short s8v __attribute__((ext_vector_type(8)));   // 8 x bf16 (bit pattern)
typedef float f4v __attribute__((ext_vector_type(4)));   // MFMA C/D + NT stores

__device__ __forceinline__ float bf2f(unsigned short h) {
    union { unsigned int u; float f; } c; c.u = ((unsigned int)h) << 16; return c.f;
}
__device__ __forceinline__ unsigned short f2bf(float x) {
    union { float f; unsigned int u; } c; c.f = x;
    return (unsigned short)((c.u + 0x7FFFu + ((c.u >> 16) & 1u)) >> 16);  // RNE
}

// ---------- prep 1: kb = bf16(k * KSCALE) ----------
__global__ void sdpa_prep_cast_k(const float* __restrict__ k, unsigned short* __restrict__ kb) {
    int i = blockIdx.x * 256 + threadIdx.x;           // grid covers exactly n/4 float4s
    float4 v = ((const float4*)k)[i];
    ushort4 o;
    o.x = f2bf(v.x * KSCALE);
    o.y = f2bf(v.y * KSCALE);
    o.z = f2bf(v.z * KSCALE);
    o.w = f2bf(v.w * KSCALE);
    ((ushort4*)kb)[i] = o;
}

// ---------- prep 2: vtb[bh][d][s] = bf16(v[bh][s][d])  (64x64 LDS tile transpose) ----------
__global__ void sdpa_prep_transpose_v(const float* __restrict__ v, unsigned short* __restrict__ vt) {
    __shared__ float t[64][65];
    const int bh = blockIdx.x >> 5;
    const int kt = blockIdx.x & 31;
    const int tid = threadIdx.x;
    const float* src = v + ((size_t)bh * SDIM + (size_t)kt * 64) * DDIM;
    #pragma unroll
    for (int i = 0; i < 4; ++i) {
        int idx = i * 256 + tid;
        int kl = idx >> 4, c4 = idx & 15;
        float4 val = ((const float4*)(src + kl * DDIM))[c4];
        t[kl][c4 * 4 + 0] = val.x; t[kl][c4 * 4 + 1] = val.y;
        t[kl][c4 * 4 + 2] = val.z; t[kl][c4 * 4 + 3] = val.w;
    }
    __syncthreads();
    const int d   = tid >> 2;
    const int klb = (tid & 3) << 4;
    unsigned short* dst = vt + ((size_t)bh * DDIM + d) * SDIM + kt * 64 + klb;
    #pragma unroll
    for (int c = 0; c < 4; ++c) {
        ushort4 w;
        w.x = f2bf(t[klb + c * 4 + 0][d]);
        w.y = f2bf(t[klb + c * 4 + 1][d]);
        w.z = f2bf(t[klb + c * 4 + 2][d]);
        w.w = f2bf(t[klb + c * 4 + 3][d]);
        ((ushort4*)dst)[c] = w;
    }
}

// ---------- main fused kernel: one block = 16 q-rows of one (b,h), 512 threads ----------
// LDS: sc[16][2048] bf16 = 65536 B (2 blocks/CU -> 16 waves/CU with 512-thread blocks).
// 16B-block XOR swizzle: element (row, col) -> row*2048 + ((col>>3) ^ row)*8 + (col&7)
// Softmax: one wave per row (2 passes of 8 rows), 32 cols/lane -> float s[32] stays
// in VGPRs (Round-3's 64-col/thread version spilled: VGPR_Count=64 + scratch traffic).
__launch_bounds__(512, 4)
__global__ void sdpa_main(const float* __restrict__ q,
                          const unsigned short* __restrict__ kb,
                          const unsigned short* __restrict__ vtb,
                          const int* __restrict__ mask,
                          float* __restrict__ outO,
                          float* __restrict__ outP) {
    extern __shared__ char lds[];
    unsigned short* sc = (unsigned short*)lds;

    const int bx = blockIdx.x;
    const int bh = bx >> 7;            // 128 q-tiles per (b,h)
    const int q0 = (bx & 127) << 4;
    const int b  = bh >> 3;            // H = 8

    const int tid  = threadIdx.x;
    const int wave = tid >> 6;         // 0..7
    const int lane = tid & 63;
    const int l15  = lane & 15;
    const int quad = lane >> 4;

    // ---- Q A-fragments straight from global fp32: A[m=l15][k=ka*32+quad*8+j] ----
    s8v aq0, aq1;
    {
        const float* qr = q + ((size_t)bh * SDIM + q0 + l15) * DDIM + quad * 8;
        float4 x0 = ((const float4*)qr)[0];
        float4 x1 = ((const float4*)qr)[1];
        float4 y0 = ((const float4*)(qr + 32))[0];
        float4 y1 = ((const float4*)(qr + 32))[1];
        aq0[0]=(short)f2bf(x0.x); aq0[1]=(short)f2bf(x0.y); aq0[2]=(short)f2bf(x0.z); aq0[3]=(short)f2bf(x0.w);
        aq0[4]=(short)f2bf(x1.x); aq0[5]=(short)f2bf(x1.y); aq0[6]=(short)f2bf(x1.z); aq0[7]=(short)f2bf(x1.w);
        aq1[0]=(short)f2bf(y0.x); aq1[1]=(short)f2bf(y0.y); aq1[2]=(short)f2bf(y0.z); aq1[3]=(short)f2bf(y0.w);
        aq1[4]=(short)f2bf(y1.x); aq1[5]=(short)f2bf(y1.y); aq1[6]=(short)f2bf(y1.z); aq1[7]=(short)f2bf(y1.w);
    }

    // ---- phase 1: scores' = Q*(K*KSCALE)^T, wave w owns kpos [256w, 256w+256) ----
    {
        const unsigned short* kbase = kb + (size_t)bh * SDIM * DDIM;
        const int n_start = wave << 8;
        #pragma unroll 2
        for (int t = 0; t < 16; ++t) {
            const int n0 = n_start + (t << 4);
            const unsigned short* krow = kbase + (size_t)(n0 + l15) * DDIM + quad * 8;
            s8v b0 = *(const s8v*)(krow);
            s8v b1 = *(const s8v*)(krow + 32);
            f4v acc = {0.f, 0.f, 0.f, 0.f};
            acc = __builtin_amdgcn_mfma_f32_16x16x32_bf16(aq0, b0, acc, 0, 0, 0);
            acc = __builtin_amdgcn_mfma_f32_16x16x32_bf16(aq1, b1, acc, 0, 0, 0);
            const int col = n0 + l15;
            const int blk = col >> 3;
            const int off = col & 7;
            #pragma unroll
            for (int r = 0; r < 4; ++r) {
                int row = quad * 4 + r;                       // C row = q-row
                sc[row * 2048 + (((blk ^ row) << 3) | off)] = f2bf(acc[r]);
            }
        }
    }

    // ---- prefetch pass-0 mask (row = wave) before the barrier: hides HBM latency ----
    const int* mbase = mask + (size_t)b * SDIM * SDIM + (size_t)q0 * SDIM;
    int4 ma[8];
    {
        const int4* mrow = (const int4*)(mbase + (size_t)wave * SDIM);
        #pragma unroll
        for (int i = 0; i < 4; ++i) {
            const int blk = lane + (i << 6);
            ma[2 * i + 0] = mrow[blk * 2 + 0];
            ma[2 * i + 1] = mrow[blk * 2 + 1];
        }
    }
    __syncthreads();

    // ---- softmax: wave w owns rows {w, w+8}; 64 lanes x 32 cols, all state in VGPRs ----
    #pragma unroll
    for (int pass = 0; pass < 2; ++pass) {
        const int row = wave + (pass << 3);
        unsigned short* scrow = sc + row * 2048;

        float s[32];
        float rmax = -3.0e38f;
        #pragma unroll
        for (int i = 0; i < 4; ++i) {
            const int blk = lane + (i << 6);                 // 8-col block index
            s8v vv = *(const s8v*)(scrow + ((blk ^ row) << 3));
            const int4 m0 = ma[2 * i + 0];
            const int4 m1 = ma[2 * i + 1];
            const int mm[8] = { m0.x, m0.y, m0.z, m0.w, m1.x, m1.y, m1.z, m1.w };
            #pragma unroll
            for (int e = 0; e < 8; ++e) {
                float x = bf2f((unsigned short)vv[e]);
                x = (mm[e] == 0) ? -1.0e9f : x;
                s[i * 8 + e] = x;
                rmax = fmaxf(rmax, x);
            }
        }
        if (pass == 0) {                                     // prefetch pass-1 mask; overlaps exp
            const int4* mrow = (const int4*)(mbase + (size_t)(wave + 8) * SDIM);
            #pragma unroll
            for (int i = 0; i < 4; ++i) {
                const int blk = lane + (i << 6);
                ma[2 * i + 0] = mrow[blk * 2 + 0];
                ma[2 * i + 1] = mrow[blk * 2 + 1];
            }
        }
        #pragma unroll
        for (int d = 1; d < 64; d <<= 1) rmax = fmaxf(rmax, __shfl_xor(rmax, d));

        float rsum = 0.f;
        #pragma unroll
        for (int i = 0; i < 32; ++i) {
            float e = exp2f(s[i] - rmax);                    // base-2: log2e folded into K
            s[i] = e;
            rsum += e;
        }
        #pragma unroll
        for (int d = 1; d < 64; d <<= 1) rsum += __shfl_xor(rsum, d);
        const float rinv = 1.0f / rsum;

        float* prow = outP + (size_t)bh * SDIM * SDIM + (size_t)(q0 + row) * SDIM;
        #pragma unroll
        for (int i = 0; i < 4; ++i) {
            const int blk = lane + (i << 6);
            float p0 = s[i*8+0] * rinv, p1 = s[i*8+1] * rinv;
            float p2 = s[i*8+2] * rinv, p3 = s[i*8+3] * rinv;
            float p4 = s[i*8+4] * rinv, p5 = s[i*8+5] * rinv;
            float p6 = s[i*8+6] * rinv, p7 = s[i*8+7] * rinv;
            f4v o0 = { p0, p1, p2, p3 };
            f4v o1 = { p4, p5, p6, p7 };
            __builtin_nontemporal_store(o0, (f4v*)prow + blk * 2 + 0);   // 537 MB stream:
            __builtin_nontemporal_store(o1, (f4v*)prow + blk * 2 + 1);   // don't pollute L2
            s8v vv;
            vv[0]=(short)f2bf(p0); vv[1]=(short)f2bf(p1); vv[2]=(short)f2bf(p2); vv[3]=(short)f2bf(p3);
            vv[4]=(short)f2bf(p4); vv[5]=(short)f2bf(p5); vv[6]=(short)f2bf(p6); vv[7]=(short)f2bf(p7);
            *(s8v*)(scrow + ((blk ^ row) << 3)) = vv;
        }
    }
    __syncthreads();

    // ---- phase 4: O = P * V. Wave w: d-tile (w&3), k-half (w>>2). ----
    {
        const int dt = wave & 3;
        const int kh = wave >> 2;
        const unsigned short* vbase = vtb + ((size_t)bh * DDIM + (dt << 4) + l15) * SDIM
                                          + (kh << 10) + quad * 8;
        const unsigned short* arow = sc + l15 * 2048;        // A row m = l15 (q-row)
        f4v acc0 = {0,0,0,0}, acc1 = {0,0,0,0};
        #pragma unroll 4
        for (int ks = 0; ks < 32; ++ks) {
            const int k0 = (kh << 10) + (ks << 5);
            s8v a  = *(const s8v*)(arow + ((((k0 >> 3) + quad) ^ l15) << 3));
            s8v bb = *(const s8v*)(vbase + (ks << 5));
            if (ks & 1) acc1 = __builtin_amdgcn_mfma_f32_16x16x32_bf16(a, bb, acc1, 0, 0, 0);
            else        acc0 = __builtin_amdgcn_mfma_f32_16x16x32_bf16(a, bb, acc0, 0, 0, 0);
        }
        f4v acc = acc0 + acc1;

        __syncthreads();                                     // everyone done reading sc
        float* scratch = (float*)lds;                        // reuse score LDS: 4 KB
        if (kh == 1) {
            #pragma unroll
            for (int r = 0; r < 4; ++r)
                scratch[(dt << 8) + ((quad * 4 + r) << 4) + l15] = acc[r];
        }
        __syncthreads();
        if (kh == 0) {
            float* orow = outO + ((size_t)bh * SDIM + q0) * DDIM + (dt << 4) + l15;
            #pragma unroll
            for (int r = 0; r < 4; ++r)
                orow[(quad * 4 + r) * DDIM] = acc[r] + scratch[(dt << 8) + ((quad * 4 + r) << 4) + l15];
        }
    }
}

extern "C" void kernel_launch(void* const* d_in, const int* in_sizes, int n_in,
                              void* d_out, int out_size, void* d_ws, size_t ws_size,
                              hipStream_t stream) {
    const float* q  = (const float*)d_in[0];
    const float* k  = (const float*)d_in[1];
    const float* v  = (const float*)d_in[2];
    const int* mask = (const int*)d_in[3];

    const size_t qkv_elems = (size_t)NB * NH * SDIM * DDIM;     // 4,194,304
    float* outO = (float*)d_out;
    float* outP = (float*)d_out + qkv_elems;

    unsigned short* kb  = (unsigned short*)d_ws;                // 8 MB
    unsigned short* vtb = kb + qkv_elems;                       // 8 MB

    sdpa_prep_cast_k<<<(int)(qkv_elems / 1024), 256, 0, stream>>>(k, kb);
    sdpa_prep_transpose_v<<<NB * NH * (SDIM / 64), 256, 0, stream>>>(v, vtb);
    sdpa_main<<<NB * NH * (SDIM / 16), 512, 65536, stream>>>(q, kb, vtb, mask, outO, outP);
}